// Round 4
// baseline (6085.217 us; speedup 1.0000x reference)
//
#include <hip/hip_runtime.h>

#define TPB 256
#define TSTEPS 512

#define LD4(p) (*reinterpret_cast<const float4*>(p))
#define ST4(p, v) (*reinterpret_cast<float4*>(p) = (v))

// ---- LDS layout (float offsets) ----
#define OFF_WS   0                   // [256][68]  raw Whh stage (row g, padded)
#define OFF_WIP  17408               // [16][64] float4: Wih packed (i, cell) -> 4 gate rows
#define OFF_XS   (OFF_WIP + 4096)    // per-wave [16][17 float4] X chunk
#define OFF_HS   (OFF_XS + 4352)     // per-wave [64] float4: h[b0..3][cell]
#define OFF_HS2  (OFF_HS + 1024)     // per-wave [4][68]: h b-major (decoder head)
#define OFF_PS   (OFF_HS2 + 1088)    // per-wave [16][8]: prev feedback
#define OFF_HP   (OFF_PS + 512)      // [16][68] head weights
#define OFF_HB   (OFF_HP + 1088)     // [16] head bias
#define SMEM_FLOATS (OFF_HB + 16)    // 29584 floats = 118336 B
#define SMEM_BYTES  (SMEM_FLOATS * 4)

__device__ __forceinline__ float fast_rcp(float x) {
  float r; asm("v_rcp_f32 %0, %1" : "=v"(r) : "v"(x)); return r;
}
__device__ __forceinline__ float sigf(float x) {
  return fast_rcp(1.f + __expf(-x));
}
__device__ __forceinline__ float tanh_f(float x) {
  float y = fminf(fmaxf(x, -15.f), 15.f);
  float e = __expf(2.f * y);
  return (e - 1.f) * fast_rcp(e + 1.f);
}

// acc (float4 over gate types i,f,g,o) += s * w
#define FMA4(A, s, W) do { \
  A.x += (s) * (W).x; A.y += (s) * (W).y; A.z += (s) * (W).z; A.w += (s) * (W).w; \
} while (0)

// LSTM cell for one batch row: A=(i,f,g,o) gates, CC=c-state reg, HH=output h
#define GATE4(A, CC, HH) do { \
  const float ig_ = sigf(A.x), fg_ = sigf(A.y), gg_ = tanh_f(A.z), og_ = sigf(A.w); \
  CC = fg_ * CC + ig_ * gg_; HH = og_ * tanh_f(CC); \
} while (0)

// gates GEMM: a0..a3 = bias + x*WihT (LDS wip) + h*WhhT (register wt[])
// XBASE rows: float4 per input-dim i holding x[b0..b3][i]; stride in floats.
#define GEMM_STEP(XBASE, XSTRIDE) \
  float4 a0 = bi, a1 = bi, a2 = bi, a3 = bi; \
  _Pragma("unroll") \
  for (int i = 0; i < 16; ++i) { \
    const float4 xv = LD4((XBASE) + i * (XSTRIDE)); \
    const float4 wv = LD4(wip + (i * 64 + l) * 4); \
    FMA4(a0, xv.x, wv); FMA4(a1, xv.y, wv); FMA4(a2, xv.z, wv); FMA4(a3, xv.w, wv); \
  } \
  _Pragma("unroll") \
  for (int k = 0; k < 64; ++k) { \
    const float4 xv = LD4(hsw + k * 4); /* wave-uniform broadcast read */ \
    FMA4(a0, xv.x, wt[k]); FMA4(a1, xv.y, wt[k]); FMA4(a2, xv.z, wt[k]); FMA4(a3, xv.w, wt[k]); \
  }

// cooperative (256-thread) staging of one phase's weights into LDS
__device__ __forceinline__ void stage_phase(const float* __restrict__ Whh,
                                            const float* __restrict__ Wih,
                                            float* Ws, float* wip, int tid) {
  // Ws[g][k], row stride 68 (16B-aligned rows, spread banks for the gather)
  #pragma unroll
  for (int k4 = 0; k4 < 16; ++k4)
    ST4(Ws + tid * 68 + k4 * 4, LD4(Whh + tid * 64 + k4 * 4));
  // wip[i][cell] = float4(W[cell][i], W[cell+64][i], W[cell+128][i], W[cell+192][i])
  const int cell = tid & 63, m = tid >> 6;
  #pragma unroll
  for (int i4 = 0; i4 < 4; ++i4) {
    const float4 v = LD4(Wih + (cell + 64 * m) * 16 + i4 * 4);
    wip[((i4 * 4 + 0) * 64 + cell) * 4 + m] = v.x;
    wip[((i4 * 4 + 1) * 64 + cell) * 4 + m] = v.y;
    wip[((i4 * 4 + 2) * 64 + cell) * 4 + m] = v.z;
    wip[((i4 * 4 + 3) * 64 + cell) * 4 + m] = v.w;
  }
}

__global__ void __launch_bounds__(TPB, 1) lstm_seq2seq(
    const float* __restrict__ X,    const float* __restrict__ eWih,
    const float* __restrict__ eWhh, const float* __restrict__ eb,
    const float* __restrict__ dWih, const float* __restrict__ dWhh,
    const float* __restrict__ db,   const float* __restrict__ hW,
    const float* __restrict__ hb,   float* __restrict__ out)
{
  extern __shared__ float sm[];
  const int tid = threadIdx.x;
  const int w = tid >> 6, l = tid & 63;   // wave w owns batch rows bb0..bb0+3; lane l owns cell l
  const int bb0 = blockIdx.x * 16 + w * 4;

  float* Ws   = sm + OFF_WS;
  float* wip  = sm + OFF_WIP;
  float* xsw  = sm + OFF_XS  + w * 1088;
  float* hsw  = sm + OFF_HS  + w * 256;
  float* hs2w = sm + OFF_HS2 + w * 272;
  float* psw  = sm + OFF_PS  + w * 128;
  float* hp   = sm + OFF_HP;
  float* hbs  = sm + OFF_HB;

  // ---------------- encoder weights: stage -> registers ----------------
  stage_phase(eWhh, eWih, Ws, wip, tid);
  __syncthreads();

  float4 wt[64];  // Whh gate rows (i,f,g,o) for cell l, all 64 k — 256 VGPRs, static-indexed only
  #pragma unroll
  for (int k = 0; k < 64; ++k)
    wt[k] = make_float4(Ws[l * 68 + k], Ws[(l + 64) * 68 + k],
                        Ws[(l + 128) * 68 + k], Ws[(l + 192) * 68 + k]);
  float4 bi = make_float4(eb[l], eb[l + 64], eb[l + 128], eb[l + 192]);

  ST4(hsw + l * 4, make_float4(0.f, 0.f, 0.f, 0.f));
  float cc0 = 0.f, cc1 = 0.f, cc2 = 0.f, cc3 = 0.f;

  // ---------------- encoder: 512 steps, zero barriers (wave-local) ----------------
  for (int t = 0; t < TSTEPS; ++t) {
    const int tt = t & 15;
    if (tt == 0) {
      // wave-local staging of X[bb0..+3][t..t+15][0..15] -> xsw[ts][i][b0..3]
      const int ts = (l >> 2) & 15, i0 = l & 3;
      #pragma unroll
      for (int r = 0; r < 4; ++r) {
        const float4 v = LD4(X + ((size_t)(bb0 + r) * TSTEPS + (t + ts)) * 16 + i0 * 4);
        xsw[ts * 68 + (i0 * 4 + 0) * 4 + r] = v.x;
        xsw[ts * 68 + (i0 * 4 + 1) * 4 + r] = v.y;
        xsw[ts * 68 + (i0 * 4 + 2) * 4 + r] = v.z;
        xsw[ts * 68 + (i0 * 4 + 3) * 4 + r] = v.w;
      }
    }
    const float* xrow = xsw + tt * 68;
    GEMM_STEP(xrow, 4);
    float h0, h1, h2, h3;
    GATE4(a0, cc0, h0); GATE4(a1, cc1, h1); GATE4(a2, cc2, h2); GATE4(a3, cc3, h3);
    ST4(hsw + l * 4, make_float4(h0, h1, h2, h3));
  }

  // ---------------- decoder weights: restage -> registers ----------------
  __syncthreads();  // all waves done reading enc Ws/wip
  stage_phase(dWhh, dWih, Ws, wip, tid);
  {
    const int o = tid >> 4, k4 = tid & 15;
    ST4(hp + o * 68 + k4 * 4, LD4(hW + o * 64 + k4 * 4));
    if (tid < 16) hbs[tid] = hb[tid];
  }
  if (l < 32) ST4(psw + l * 4, make_float4(0.f, 0.f, 0.f, 0.f));  // BOS prev = 0
  __syncthreads();

  #pragma unroll
  for (int k = 0; k < 64; ++k)
    wt[k] = make_float4(Ws[l * 68 + k], Ws[(l + 64) * 68 + k],
                        Ws[(l + 128) * 68 + k], Ws[(l + 192) * 68 + k]);
  bi = make_float4(db[l], db[l + 64], db[l + 128], db[l + 192]);

  // ---------------- decoder: 512 autoregressive steps, zero barriers ----------------
  const int rr = l >> 4, oo = l & 15;
  for (int t = 0; t < TSTEPS; ++t) {
    GEMM_STEP(psw, 8);
    float h0, h1, h2, h3;
    GATE4(a0, cc0, h0); GATE4(a1, cc1, h1); GATE4(a2, cc2, h2); GATE4(a3, cc3, h3);
    ST4(hsw + l * 4, make_float4(h0, h1, h2, h3));
    hs2w[0 * 68 + l] = h0; hs2w[1 * 68 + l] = h1;
    hs2w[2 * 68 + l] = h2; hs2w[3 * 68 + l] = h3;
    // head: lane (rr, oo) computes pred[bb0+rr][oo]
    float acc = hbs[oo];
    const float* h2r = hs2w + rr * 68;
    const float* wr  = hp + oo * 68;
    #pragma unroll
    for (int k4 = 0; k4 < 16; ++k4) {
      const float4 hv = LD4(h2r + k4 * 4);
      const float4 wv = LD4(wr + k4 * 4);
      acc += hv.x * wv.x + hv.y * wv.y + hv.z * wv.z + hv.w * wv.w;
    }
    out[((size_t)(bb0 + rr) * TSTEPS + t) * 16 + oo] = acc;
    psw[oo * 8 + rr] = acc;  // feedback
  }
}

extern "C" void kernel_launch(void* const* d_in, const int* in_sizes, int n_in,
                              void* d_out, int out_size, void* d_ws, size_t ws_size,
                              hipStream_t stream) {
  (void)in_sizes; (void)n_in; (void)d_ws; (void)ws_size; (void)out_size;
  const float* X    = (const float*)d_in[0];
  const float* eWih = (const float*)d_in[1];
  const float* eWhh = (const float*)d_in[2];
  const float* eb   = (const float*)d_in[3];
  const float* dWih = (const float*)d_in[4];
  const float* dWhh = (const float*)d_in[5];
  const float* db   = (const float*)d_in[6];
  const float* hW   = (const float*)d_in[7];
  const float* hb   = (const float*)d_in[8];
  float* out = (float*)d_out;

  hipFuncSetAttribute(reinterpret_cast<const void*>(lstm_seq2seq),
                      hipFuncAttributeMaxDynamicSharedMemorySize, SMEM_BYTES);
  lstm_seq2seq<<<dim3(256), dim3(TPB), SMEM_BYTES, stream>>>(
      X, eWih, eWhh, eb, dWih, dWhh, db, hW, hb, out);
}

// Round 7
// 2807.318 us; speedup vs baseline: 2.1676x; 2.1676x over previous
//
#include <hip/hip_runtime.h>

#define TPB 512
#define TSTEPS 512

#define LD4(p) (*reinterpret_cast<const float4*>(p))
#define ST4(p, v) (*reinterpret_cast<float4*>(p) = (v))

// ---- LDS layout (float offsets) ----
#define P_PART 0                    // 20480: partials [4g][2buf][2kap][64][20]; aliases Ws[256][68] during staging
#define P_WIP  20480                // 4096: Wih/dWih packed [16 i][64 cell] float4(gates)
#define P_HW   (P_WIP + 4096)       // 1088: head W [16 o][68]
#define P_HB   (P_HW + 1088)        // 16
#define P_XS   (P_HB + 16)          // 4096: per-wave [16 t][8 i][4 r] x chunk (own i-half)
#define P_HSW  (P_XS + 4096)        // 2048: per-wave [64 cell] float4 h (own copy)
#define P_HS2  (P_HSW + 2048)       // 2176: per-wave [4 r][68] h b-major (head)
#define SMEM_FLOATS (P_HS2 + 2176)  // 34000 floats = 136000 B
#define SMEM_BYTES  (SMEM_FLOATS * 4)

__device__ __forceinline__ float fast_rcp(float x) {
  float r; asm("v_rcp_f32 %0, %1" : "=v"(r) : "v"(x)); return r;
}
__device__ __forceinline__ float sigf(float x) {
  return fast_rcp(1.f + __expf(-x));
}
__device__ __forceinline__ float tanh_f(float x) {
  float y = fminf(fmaxf(x, -15.f), 15.f);
  float e = __expf(2.f * y);
  return (e - 1.f) * fast_rcp(e + 1.f);
}

#define FMA4(A, s, W) do { \
  A.x += (s) * (W).x; A.y += (s) * (W).y; A.z += (s) * (W).z; A.w += (s) * (W).w; \
} while (0)
#define ADDP(A, PTR) do { const float4 p_ = LD4(PTR); \
  A.x += p_.x; A.y += p_.y; A.z += p_.z; A.w += p_.w; } while (0)
#define GATE4(A, CC, HH) do { \
  const float ig_ = sigf(A.x), fg_ = sigf(A.y), gg_ = tanh_f(A.z), og_ = sigf(A.w); \
  CC = fg_ * CC + ig_ * gg_; HH = og_ * tanh_f(CC); \
} while (0)

// one full decoder step (k-split GEMM + exchange + cell + head); 1 barrier
#define DEC_STEP(t) do { \
    float4 a0 = bi, a1 = bi, a2 = bi, a3 = bi; \
    _Pragma("unroll") \
    for (int kk = 0; kk < 32; ++kk) { \
      const float4 xv = LD4(hsw + (KB + kk) * 4); \
      FMA4(a0, xv.x, wt[kk]); FMA4(a1, xv.y, wt[kk]); \
      FMA4(a2, xv.z, wt[kk]); FMA4(a3, xv.w, wt[kk]); \
    } \
    float* pw = partg + (((t) & 1) * 2 + kap) * 1280 + l * 20; \
    ST4(pw, a0); ST4(pw + 4, a1); ST4(pw + 8, a2); ST4(pw + 12, a3); \
    __syncthreads(); \
    const float* pr = partg + (((t) & 1) * 2 + (kap ^ 1)) * 1280 + l * 20; \
    ADDP(a0, pr); ADDP(a1, pr + 4); ADDP(a2, pr + 8); ADDP(a3, pr + 12); \
    float h0, h1, h2, h3; \
    GATE4(a0, cc0, h0); GATE4(a1, cc1, h1); GATE4(a2, cc2, h2); GATE4(a3, cc3, h3); \
    ST4(hsw + l * 4, make_float4(h0, h1, h2, h3)); \
    hs2o[0 * 68 + l] = h0; hs2o[1 * 68 + l] = h1; \
    hs2o[2 * 68 + l] = h2; hs2o[3 * 68 + l] = h3; \
    if (l < 32) { \
      const int r_ = 2 * kap + (l >> 4), o_ = l & 15; \
      float acc = hbs[o_]; \
      const float* h2r = hs2o + r_ * 68; \
      const float* wr  = hw + o_ * 68; \
      _Pragma("unroll") \
      for (int k4 = 0; k4 < 16; ++k4) { \
        const float4 hv = LD4(h2r + k4 * 4); \
        const float4 wv = LD4(wr + k4 * 4); \
        acc += hv.x * wv.x + hv.y * wv.y + hv.z * wv.z + hv.w * wv.w; \
      } \
      out[((size_t)(bb0 + r_) * TSTEPS + (t)) * 16 + o_] = acc; \
    } \
  } while (0)

// stage Whh rows -> Ws[g][68] and Wih packed -> wip (first 256 threads)
#define STAGE_W(WHH, WIH) do { \
    if (tid < 256) { \
      _Pragma("unroll") \
      for (int k4 = 0; k4 < 16; ++k4) \
        ST4(Ws + tid * 68 + k4 * 4, LD4((WHH) + tid * 64 + k4 * 4)); \
      const int cell_ = tid & 63, m_ = tid >> 6; \
      _Pragma("unroll") \
      for (int i4 = 0; i4 < 4; ++i4) { \
        const float4 v = LD4((WIH) + (cell_ + 64 * m_) * 16 + i4 * 4); \
        wip[((i4 * 4 + 0) * 64 + cell_) * 4 + m_] = v.x; \
        wip[((i4 * 4 + 1) * 64 + cell_) * 4 + m_] = v.y; \
        wip[((i4 * 4 + 2) * 64 + cell_) * 4 + m_] = v.z; \
        wip[((i4 * 4 + 3) * 64 + cell_) * 4 + m_] = v.w; \
      } \
    } \
  } while (0)

// load this lane's k-half gate rows from Ws into wt[32] (128 VGPRs)
#define LOAD_WT() do { \
    _Pragma("unroll") \
    for (int kk = 0; kk < 32; ++kk) { \
      const int k_ = KB + kk; \
      wt[kk] = make_float4(Ws[l * 68 + k_], Ws[(l + 64) * 68 + k_], \
                           Ws[(l + 128) * 68 + k_], Ws[(l + 192) * 68 + k_]); \
    } \
  } while (0)

__global__ void __launch_bounds__(TPB, 2) lstm_seq2seq(
    const float* __restrict__ X,    const float* __restrict__ eWih,
    const float* __restrict__ eWhh, const float* __restrict__ eb,
    const float* __restrict__ dWih, const float* __restrict__ dWhh,
    const float* __restrict__ db,   const float* __restrict__ hWp,
    const float* __restrict__ hbp,  float* __restrict__ out)
{
  extern __shared__ float sm[];
  const int tid = threadIdx.x;
  const int w = tid >> 6, l = tid & 63;
  const int g = w >> 1, kap = w & 1;      // batch group, k-half
  const int KB = kap * 32;
  const int bb0 = blockIdx.x * 16 + g * 4;

  float* Ws    = sm + P_PART;             // staging alias of partials region
  float* partg = sm + P_PART + g * 4 * 1280;
  float* wip   = sm + P_WIP;
  float* hw    = sm + P_HW;
  float* hbs   = sm + P_HB;
  float* xsw   = sm + P_XS  + w * 512;
  float* hsw   = sm + P_HSW + w * 256;
  float* hs2o  = sm + P_HS2 + w * 272;

  // ---------------- encoder weights ----------------
  STAGE_W(eWhh, eWih);
  __syncthreads();

  float4 wt[32];
  LOAD_WT();
  float4 wi[8];
  #pragma unroll
  for (int ii = 0; ii < 8; ++ii)
    wi[ii] = LD4(wip + ((kap * 8 + ii) * 64 + l) * 4);
  float4 bi = (kap == 0)
      ? make_float4(eb[l], eb[l + 64], eb[l + 128], eb[l + 192])
      : make_float4(0.f, 0.f, 0.f, 0.f);
  ST4(hsw + l * 4, make_float4(0.f, 0.f, 0.f, 0.f));
  float cc0 = 0.f, cc1 = 0.f, cc2 = 0.f, cc3 = 0.f;
  __syncthreads();                        // Ws region becomes partials now

  // ---------------- encoder: 512 steps, 1 barrier/step ----------------
  for (int t = 0; t < TSTEPS; ++t) {
    if ((t & 15) == 0) {
      // wave-local stage of own i-half: X[bb0..+3][t..t+15][kap*8..+8]
      #pragma unroll
      for (int rep = 0; rep < 2; ++rep) {
        const int q = rep * 64 + l;
        const int ts = q & 15, r = (q >> 4) & 3, iq = q >> 6;
        const float4 v = LD4(X + ((size_t)(bb0 + r) * TSTEPS + (t + ts)) * 16 + kap * 8 + iq * 4);
        xsw[ts * 32 + (iq * 4 + 0) * 4 + r] = v.x;
        xsw[ts * 32 + (iq * 4 + 1) * 4 + r] = v.y;
        xsw[ts * 32 + (iq * 4 + 2) * 4 + r] = v.z;
        xsw[ts * 32 + (iq * 4 + 3) * 4 + r] = v.w;
      }
    }
    float4 a0 = bi, a1 = bi, a2 = bi, a3 = bi;
    const float* xrow = xsw + (t & 15) * 32;
    #pragma unroll
    for (int ii = 0; ii < 8; ++ii) {      // own i-half (weights in regs)
      const float4 xv = LD4(xrow + ii * 4);
      FMA4(a0, xv.x, wi[ii]); FMA4(a1, xv.y, wi[ii]);
      FMA4(a2, xv.z, wi[ii]); FMA4(a3, xv.w, wi[ii]);
    }
    #pragma unroll
    for (int kk = 0; kk < 32; ++kk) {     // own k-half (weights in regs, h broadcast)
      const float4 xv = LD4(hsw + (KB + kk) * 4);
      FMA4(a0, xv.x, wt[kk]); FMA4(a1, xv.y, wt[kk]);
      FMA4(a2, xv.z, wt[kk]); FMA4(a3, xv.w, wt[kk]);
    }
    float* pw = partg + ((t & 1) * 2 + kap) * 1280 + l * 20;
    ST4(pw, a0); ST4(pw + 4, a1); ST4(pw + 8, a2); ST4(pw + 12, a3);
    __syncthreads();
    const float* pr = partg + ((t & 1) * 2 + (kap ^ 1)) * 1280 + l * 20;
    ADDP(a0, pr); ADDP(a1, pr + 4); ADDP(a2, pr + 8); ADDP(a3, pr + 12);
    float h0, h1, h2, h3;                 // both kap waves update redundantly (bit-identical)
    GATE4(a0, cc0, h0); GATE4(a1, cc1, h1); GATE4(a2, cc2, h2); GATE4(a3, cc3, h3);
    ST4(hsw + l * 4, make_float4(h0, h1, h2, h3));
  }

  // ---------------- decoder weights + head ----------------
  __syncthreads();                        // enc partial reads done; PART -> Ws again
  STAGE_W(dWhh, dWih);
  if (tid < 256) {
    const int o = tid >> 4, k4 = tid & 15;
    ST4(hw + o * 68 + k4 * 4, LD4(hWp + o * 64 + k4 * 4));
    if (tid < 16) hbs[tid] = hbp[tid];
  }
  __syncthreads();
  LOAD_WT();                              // wt = dWhh (step 0 uses raw weights: prev = 0)
  bi = (kap == 0)
      ? make_float4(db[l], db[l + 64], db[l + 128], db[l + 192])
      : make_float4(0.f, 0.f, 0.f, 0.f);
  __syncthreads();                        // protect Ws until all waves loaded wt

  DEC_STEP(0);

  // fold feedback into weights: wt += dWih·hW (k-half), bi += dWih·hb
  #pragma unroll
  for (int o = 0; o < 16; ++o) {
    const float4 dw = LD4(wip + (o * 64 + l) * 4);
    if (kap == 0) { const float hbo = hbs[o]; FMA4(bi, hbo, dw); }
    #pragma unroll
    for (int j = 0; j < 8; ++j) {
      const float4 hwv = LD4(hw + o * 68 + KB + j * 4);
      FMA4(wt[j * 4 + 0], hwv.x, dw);
      FMA4(wt[j * 4 + 1], hwv.y, dw);
      FMA4(wt[j * 4 + 2], hwv.z, dw);
      FMA4(wt[j * 4 + 3], hwv.w, dw);
    }
  }

  for (int t = 1; t < TSTEPS; ++t) DEC_STEP(t);
}

extern "C" void kernel_launch(void* const* d_in, const int* in_sizes, int n_in,
                              void* d_out, int out_size, void* d_ws, size_t ws_size,
                              hipStream_t stream) {
  (void)in_sizes; (void)n_in; (void)d_ws; (void)ws_size; (void)out_size;
  const float* X    = (const float*)d_in[0];
  const float* eWih = (const float*)d_in[1];
  const float* eWhh = (const float*)d_in[2];
  const float* eb   = (const float*)d_in[3];
  const float* dWih = (const float*)d_in[4];
  const float* dWhh = (const float*)d_in[5];
  const float* db   = (const float*)d_in[6];
  const float* hW   = (const float*)d_in[7];
  const float* hb   = (const float*)d_in[8];
  float* out = (float*)d_out;

  hipFuncSetAttribute(reinterpret_cast<const void*>(lstm_seq2seq),
                      hipFuncAttributeMaxDynamicSharedMemorySize, SMEM_BYTES);
  lstm_seq2seq<<<dim3(256), dim3(TPB), SMEM_BYTES, stream>>>(
      X, eWih, eWhh, eb, dWih, dWhh, db, hW, hb, out);
}

// Round 8
// 1112.170 us; speedup vs baseline: 5.4715x; 2.5242x over previous
//
#include <hip/hip_runtime.h>
#include <hip/hip_bf16.h>

#define TPB 256
#define TSTEPS 512

typedef __attribute__((ext_vector_type(8))) short bfrag;   // 8 bf16 (4 VGPRs)
typedef __attribute__((ext_vector_type(4))) float f32x4;   // MFMA C/D

#define LD4(p) (*reinterpret_cast<const float4*>(p))
#define MFMA(a, b, c) __builtin_amdgcn_mfma_f32_16x16x32_bf16((a), (b), (c), 0, 0, 0)

__device__ __forceinline__ float fast_rcp(float x) {
  float r; asm("v_rcp_f32 %0, %1" : "=v"(r) : "v"(x)); return r;
}
__device__ __forceinline__ float sigf(float x) { return fast_rcp(1.f + __expf(-x)); }
__device__ __forceinline__ float tanh_f(float x) {
  float y = fminf(fmaxf(x, -15.f), 15.f);
  float e = __expf(2.f * y);
  return (e - 1.f) * fast_rcp(e + 1.f);
}
__device__ __forceinline__ unsigned short f2bf(float f) {
  __hip_bfloat16 h = __float2bfloat16(f);
  return *reinterpret_cast<unsigned short*>(&h);
}
__device__ __forceinline__ float bf2f(unsigned short u) {
  __hip_bfloat16 h; *reinterpret_cast<unsigned short*>(&h) = u;
  return __bfloat162float(h);
}

// split 8 fp32 into hi/lo bf16 fragments (static-indexed -> registers)
#define SPLIT8(V, FH, FL) do { \
  _Pragma("unroll") \
  for (int j_ = 0; j_ < 8; ++j_) { \
    const unsigned short h_ = f2bf(V[j_]); \
    FH[j_] = (short)h_; \
    FL[j_] = (short)f2bf(V[j_] - bf2f(h_)); \
  } } while (0)

// HB: h as bf16 [buf][hl][row b][72 cells pad]  (row stride 144 B, 16B-aligned reads)
#define HBI(buf, hl, b) ((((buf)*2 + (hl))*16 + (b)) * 72)

__global__ void __launch_bounds__(TPB, 1) lstm_mfma(
    const float* __restrict__ X,    const float* __restrict__ eWih,
    const float* __restrict__ eWhh, const float* __restrict__ eb,
    const float* __restrict__ dWih, const float* __restrict__ dWhh,
    const float* __restrict__ db,   const float* __restrict__ hWp,
    const float* __restrict__ hbp,  float* __restrict__ out)
{
  __shared__ __align__(16) unsigned long long XF[4096];   // x A-frags b64-SoA: [t][dp][hl][lane]
  __shared__ __align__(16) unsigned short HB[2*2*16*72];  // h bf16 double-buffered
  __shared__ __align__(16) float HWs[16*72];              // head W fp32 (for decoder fold)
  __shared__ float HBS[16];                               // head bias

  const int tid = threadIdx.x;
  const int w = tid >> 6, l = tid & 63;        // wave w = cellblock; lane l
  const int c = l & 15, q = l >> 4;            // A-row / D-col index, k-quadrant
  const int bb0 = blockIdx.x * 16;

  // ---- init: zero XF (covers zero-pad k>=16 slots forever) + HB (h(-1)=0); stage head W ----
  for (int i = tid; i < 4096; i += TPB) XF[i] = 0ULL;
  for (int i = tid; i < 2*2*16*72; i += TPB) HB[i] = 0;
  {
    const int o = tid >> 4, k4 = tid & 15;
    *reinterpret_cast<float4*>(&HWs[o*72 + k4*4]) = LD4(hWp + o*64 + k4*4);
    if (tid < 16) HBS[tid] = hbp[tid];
  }

  // ---- encoder weight fragments (B-operand, hi/lo split, in registers) ----
  bfrag wh_h[4][2], wh_l[4][2], wi_h[4], wi_l[4];
  float bias[4];
  #pragma unroll
  for (int G = 0; G < 4; ++G) {
    const int g = G*64 + w*16 + c;             // gate row: B col = c within wave's 16 cells
    bias[G] = eb[g];
    #pragma unroll
    for (int kt = 0; kt < 2; ++kt) {
      float v[8];
      #pragma unroll
      for (int j = 0; j < 8; ++j) v[j] = eWhh[g*64 + kt*32 + q*8 + j];
      SPLIT8(v, wh_h[G][kt], wh_l[G][kt]);
    }
    {
      float v[8];
      #pragma unroll
      for (int j = 0; j < 8; ++j) { const int k = q*8 + j; v[j] = (k < 16) ? eWih[g*16 + k] : 0.f; }
      SPLIT8(v, wi_h[G], wi_l[G]);
    }
  }
  // head B-frags (used by wave 3) + head bias
  bfrag hwf_h[2], hwf_l[2];
  #pragma unroll
  for (int kt = 0; kt < 2; ++kt) {
    float v[8];
    #pragma unroll
    for (int j = 0; j < 8; ++j) v[j] = hWp[c*64 + kt*32 + q*8 + j];
    SPLIT8(v, hwf_h[kt], hwf_l[kt]);
  }
  const float hbv = hbp[c];

  float cc[4] = {0.f, 0.f, 0.f, 0.f};          // c-state: 4 batch rows (b=4q+r), cell w*16+c

  // ================ encoder: 512 steps ================
  for (int t = 0; t < TSTEPS; ++t) {
    const int tt = t & 15;
    if (tt == 0) {
      __syncthreads();                         // old-chunk XF reads done
      // stage 16-step x chunk as pre-packed hi/lo A-frags (coalesced 64B runs)
      #pragma unroll
      for (int r = 0; r < 4; ++r) {
        const int fidx = r * TPB + tid;
        const int i4 = fidx & 3, ts = (fidx >> 2) & 15, b = fidx >> 6;
        const float4 v = LD4(X + ((size_t)(bb0 + b) * TSTEPS + (t + ts)) * 16 + i4 * 4);
        const unsigned short hx = f2bf(v.x), hy = f2bf(v.y), hz = f2bf(v.z), hw2 = f2bf(v.w);
        const unsigned short lx = f2bf(v.x - bf2f(hx)), ly = f2bf(v.y - bf2f(hy)),
                             lz = f2bf(v.z - bf2f(hz)), lw = f2bf(v.w - bf2f(hw2));
        const int dp = i4 & 1, slot = (i4 >> 1) * 16 + b;
        XF[((ts*2 + dp)*2 + 0)*64 + slot] =
            (unsigned long long)((unsigned)hx | ((unsigned)hy << 16)) |
            ((unsigned long long)((unsigned)hz | ((unsigned)hw2 << 16)) << 32);
        XF[((ts*2 + dp)*2 + 1)*64 + slot] =
            (unsigned long long)((unsigned)lx | ((unsigned)ly << 16)) |
            ((unsigned long long)((unsigned)lz | ((unsigned)lw << 16)) << 32);
      }
    }
    __syncthreads();                           // h(t-1) + XF visible
    const int rb = t & 1;

    bfrag ah_h[2], ah_l[2], ax_h, ax_l;
    #pragma unroll
    for (int kt = 0; kt < 2; ++kt) {           // A-row = c(=l&15) is the BATCH row here
      ah_h[kt] = *reinterpret_cast<const bfrag*>(&HB[HBI(rb, 0, c) + kt*32 + q*8]);
      ah_l[kt] = *reinterpret_cast<const bfrag*>(&HB[HBI(rb, 1, c) + kt*32 + q*8]);
    }
    {
      union { bfrag f; unsigned long long d2[2]; } uh, ul;
      uh.d2[0] = XF[((tt*2 + 0)*2 + 0)*64 + l]; uh.d2[1] = XF[((tt*2 + 1)*2 + 0)*64 + l];
      ul.d2[0] = XF[((tt*2 + 0)*2 + 1)*64 + l]; ul.d2[1] = XF[((tt*2 + 1)*2 + 1)*64 + l];
      ax_h = uh.f; ax_l = ul.f;
    }

    f32x4 acc[4];
    #pragma unroll
    for (int G = 0; G < 4; ++G) { f32x4 z = {bias[G], bias[G], bias[G], bias[G]}; acc[G] = z; }
    #pragma unroll
    for (int G = 0; G < 4; ++G) {
      acc[G] = MFMA(ax_h, wi_h[G], acc[G]);
      acc[G] = MFMA(ax_h, wi_l[G], acc[G]);
      acc[G] = MFMA(ax_l, wi_h[G], acc[G]);
      #pragma unroll
      for (int kt = 0; kt < 2; ++kt) {
        acc[G] = MFMA(ah_h[kt], wh_h[G][kt], acc[G]);
        acc[G] = MFMA(ah_h[kt], wh_l[G][kt], acc[G]);
        acc[G] = MFMA(ah_l[kt], wh_h[G][kt], acc[G]);
      }
    }

    const int wb = rb ^ 1;
    #pragma unroll
    for (int r = 0; r < 4; ++r) {              // D row b = 4q+r, D col -> cell w*16+c
      const float ig = sigf(acc[0][r]), fg = sigf(acc[1][r]);
      const float gg = tanh_f(acc[2][r]), og = sigf(acc[3][r]);
      cc[r] = fg * cc[r] + ig * gg;
      const float h = og * tanh_f(cc[r]);
      const unsigned short hh = f2bf(h);
      const unsigned short hl2 = f2bf(h - bf2f(hh));
      const int b = q*4 + r;
      HB[HBI(wb, 0, b) + w*16 + c] = hh;
      HB[HBI(wb, 1, b) + w*16 + c] = hl2;
    }
  }

  // ---- decoder raw weights (step 0: prev=0 -> gates = dWhh*h + db) ----
  #pragma unroll
  for (int G = 0; G < 4; ++G) {
    const int g = G*64 + w*16 + c;
    bias[G] = db[g];
    #pragma unroll
    for (int kt = 0; kt < 2; ++kt) {
      float v[8];
      #pragma unroll
      for (int j = 0; j < 8; ++j) v[j] = dWhh[g*64 + kt*32 + q*8 + j];
      SPLIT8(v, wh_h[G][kt], wh_l[G][kt]);
    }
  }

  // ================ decoder: 512 autoregressive steps ================
  for (int t = 0; t < TSTEPS; ++t) {
    __syncthreads();
    const int rb = t & 1;
    bfrag ah_h[2], ah_l[2];
    #pragma unroll
    for (int kt = 0; kt < 2; ++kt) {
      ah_h[kt] = *reinterpret_cast<const bfrag*>(&HB[HBI(rb, 0, c) + kt*32 + q*8]);
      ah_l[kt] = *reinterpret_cast<const bfrag*>(&HB[HBI(rb, 1, c) + kt*32 + q*8]);
    }
    if (w == 3 && t > 0) {                     // head: pred(t-1) from h(t-1) (same A-frags)
      f32x4 hd = {hbv, hbv, hbv, hbv};
      #pragma unroll
      for (int kt = 0; kt < 2; ++kt) {
        hd = MFMA(ah_h[kt], hwf_h[kt], hd);
        hd = MFMA(ah_h[kt], hwf_l[kt], hd);
        hd = MFMA(ah_l[kt], hwf_h[kt], hd);
      }
      #pragma unroll
      for (int r = 0; r < 4; ++r)
        out[((size_t)(bb0 + q*4 + r) * TSTEPS + (t - 1)) * 16 + c] = hd[r];
    }

    f32x4 acc[4];
    #pragma unroll
    for (int G = 0; G < 4; ++G) { f32x4 z = {bias[G], bias[G], bias[G], bias[G]}; acc[G] = z; }
    #pragma unroll
    for (int G = 0; G < 4; ++G) {
      #pragma unroll
      for (int kt = 0; kt < 2; ++kt) {
        acc[G] = MFMA(ah_h[kt], wh_h[G][kt], acc[G]);
        acc[G] = MFMA(ah_h[kt], wh_l[G][kt], acc[G]);
        acc[G] = MFMA(ah_l[kt], wh_h[G][kt], acc[G]);
      }
    }

    const int wb = rb ^ 1;
    #pragma unroll
    for (int r = 0; r < 4; ++r) {
      const float ig = sigf(acc[0][r]), fg = sigf(acc[1][r]);
      const float gg = tanh_f(acc[2][r]), og = sigf(acc[3][r]);
      cc[r] = fg * cc[r] + ig * gg;
      const float h = og * tanh_f(cc[r]);
      const unsigned short hh = f2bf(h);
      const unsigned short hl2 = f2bf(h - bf2f(hh));
      const int b = q*4 + r;
      HB[HBI(wb, 0, b) + w*16 + c] = hh;
      HB[HBI(wb, 1, b) + w*16 + c] = hl2;
    }

    if (t == 0) {                              // fold feedback: W += dWih*hW, b += dWih*hb
      #pragma unroll
      for (int G = 0; G < 4; ++G) {
        const int g = G*64 + w*16 + c;
        float dwv[16];
        #pragma unroll
        for (int o4 = 0; o4 < 4; ++o4) {
          const float4 v = LD4(dWih + g*16 + o4*4);
          dwv[o4*4+0] = v.x; dwv[o4*4+1] = v.y; dwv[o4*4+2] = v.z; dwv[o4*4+3] = v.w;
        }
        float bb = db[g];
        #pragma unroll
        for (int o = 0; o < 16; ++o) bb += dwv[o] * HBS[o];
        bias[G] = bb;
        #pragma unroll
        for (int kt = 0; kt < 2; ++kt) {
          float v[8];
          #pragma unroll
          for (int j = 0; j < 8; ++j) {
            const int k = kt*32 + q*8 + j;
            float ww = dWhh[g*64 + k];
            #pragma unroll
            for (int o = 0; o < 16; ++o) ww += dwv[o] * HWs[o*72 + k];
            v[j] = ww;
          }
          SPLIT8(v, wh_h[G][kt], wh_l[G][kt]);
        }
      }
    }
  }

  // ---- epilogue: pred(511) from h(511) ----
  __syncthreads();
  if (w == 3) {
    const int rb = TSTEPS & 1;                 // buffer holding h(511)
    bfrag ah_h[2], ah_l[2];
    #pragma unroll
    for (int kt = 0; kt < 2; ++kt) {
      ah_h[kt] = *reinterpret_cast<const bfrag*>(&HB[HBI(rb, 0, c) + kt*32 + q*8]);
      ah_l[kt] = *reinterpret_cast<const bfrag*>(&HB[HBI(rb, 1, c) + kt*32 + q*8]);
    }
    f32x4 hd = {hbv, hbv, hbv, hbv};
    #pragma unroll
    for (int kt = 0; kt < 2; ++kt) {
      hd = MFMA(ah_h[kt], hwf_h[kt], hd);
      hd = MFMA(ah_h[kt], hwf_l[kt], hd);
      hd = MFMA(ah_l[kt], hwf_h[kt], hd);
    }
    #pragma unroll
    for (int r = 0; r < 4; ++r)
      out[((size_t)(bb0 + q*4 + r) * TSTEPS + (TSTEPS - 1)) * 16 + c] = hd[r];
  }
}

extern "C" void kernel_launch(void* const* d_in, const int* in_sizes, int n_in,
                              void* d_out, int out_size, void* d_ws, size_t ws_size,
                              hipStream_t stream) {
  (void)in_sizes; (void)n_in; (void)d_ws; (void)ws_size; (void)out_size;
  const float* X    = (const float*)d_in[0];
  const float* eWih = (const float*)d_in[1];
  const float* eWhh = (const float*)d_in[2];
  const float* eb   = (const float*)d_in[3];
  const float* dWih = (const float*)d_in[4];
  const float* dWhh = (const float*)d_in[5];
  const float* db   = (const float*)d_in[6];
  const float* hW   = (const float*)d_in[7];
  const float* hb   = (const float*)d_in[8];
  float* out = (float*)d_out;

  lstm_mfma<<<dim3(256), dim3(TPB), 0, stream>>>(
      X, eWih, eWhh, eb, dWih, dWhh, db, hW, hb, out);
}